// Round 10
// baseline (416.662 us; speedup 1.0000x reference)
//
#include <hip/hip_runtime.h>
#include <stdint.h>

#define N_ROWS 8192
#define H_DIM  1024
#define I_DIM  4096

typedef unsigned short u16;
typedef __bf16 bf16x8 __attribute__((ext_vector_type(8)));
typedef float f32x16 __attribute__((ext_vector_type(16)));
typedef u16 u16x4 __attribute__((ext_vector_type(4)));

#define BAR()   asm volatile("s_barrier" ::: "memory")
#define VMW(n)  asm volatile("s_waitcnt vmcnt(" #n ")" ::: "memory")

__device__ __forceinline__ u16 f2bf(float f) {
    union { float f; uint32_t u; } v; v.f = f;
    uint32_t u = v.u;
    u += 0x7FFFu + ((u >> 16) & 1u);   // RNE
    return (u16)(u >> 16);
}

__device__ __forceinline__ float bf2f(u16 h) {
    union { uint32_t u; float f; } v; v.u = ((uint32_t)h) << 16;
    return v.f;
}

__device__ __forceinline__ float gelu_tanh(float x) {
    float u = 0.7978845608028654f * (x + 0.044715f * x * x * x);
    u = fminf(fmaxf(u, -15.f), 15.f);
    float e = __expf(2.f * u);
    float t = (e - 1.f) / (e + 1.f);
    return 0.5f * x * (1.f + t);
}

// ---- global -> LDS direct (16B per lane) ----
__device__ __forceinline__ void load_lds16(const void* g, void* l) {
    auto gp = reinterpret_cast<const __attribute__((address_space(1))) uint32_t*>(
        reinterpret_cast<uintptr_t>(g));
    auto lp = reinterpret_cast<__attribute__((address_space(3))) uint32_t*>(
        static_cast<uint32_t>(reinterpret_cast<uintptr_t>(l)));
    __builtin_amdgcn_global_load_lds(gp, lp, 16, 0, 0);
}

// =====================================================================
// GEMM1 (B-direct + 32x32x16): hid = gelu(xln·W1g^T+bg)*(xln·W1l^T+bl)
// Tile 256 rows x 128 hid-cols; 512 thr / 8 waves (2M x 4N); per-wave
// 128 rows x (32 gate + 32 lin) cols as 4 Mtiles x 2 Ntiles of 32x32.
// A: LDS ring-3 x 16 KiB (A[256][32] u16, 48 KiB total), staged t+2 via
//   global_load_lds; swizzle s(r)=((r>>1)&3)^((r>>3)&3) on k-granules
//   (uniform 8-lane/quad for 32-row ds_read_b128 fragments).
// B: DIRECT global->VGPR (wave-private cols, zero block reuse -> LDS
//   staging was pure overhead). Double-buffered regs, prefetch t+1.
//   Per-lane: col = base + (lane&31), k = k0 + ks*16 + (lane>>5)*8.
// MFMA: f32_32x32x16_bf16; C-layout col=lane&31,
//   row=(reg&3)+8*(reg>>2)+4*(lane>>5)  [HW-verified m74/m101].
// Sync/iter: issue {2 A-gloads, SB(0), 4 B-loads}; 8 ds_read; 16 MFMA;
//   VMW(6) (=this iter's ops; guarantees A(t+1) landed); BAR.
//   Compiler's B-register waits cover prologue/tail transitives.
// =====================================================================
__global__ __launch_bounds__(512, 2) void gemm1_gated(
    const u16* __restrict__ A, const u16* __restrict__ W,
    const float* __restrict__ bias, u16* __restrict__ hid)
{
    __shared__ u16 lds[3 * 8192];      // 48 KiB
    const int t = threadIdx.x;
    const int lane = t & 63, wid = t >> 6;
    const int wm = wid >> 2, wn = wid & 3;
    const int cl = lane & 31, kh = lane >> 5;

    const int brow = blockIdx.y * 256;
    const int bcol = blockIdx.x * 128;

    // staging constants: thread t covers A rows tr and tr+128, granule t&3
    const int tr = t >> 2;
    const int sstg = ((tr >> 1) & 3) ^ ((tr >> 3) & 3);
    const int swz8 = ((t & 3) ^ sstg) * 8;
    const u16* pA = A + (size_t)(brow + tr) * H_DIM + swz8;
    const int dst = t * 8;

    // ds_read constants (u16 units)
    const int s  = ((cl >> 1) & 3) ^ ((cl >> 3) & 3);
    const int p0 = ((0 + kh) ^ s) * 8;         // ks0 physical granule
    const int p1 = ((2 + kh) ^ s) * 8;         // ks1 physical granule
    const int rdA = (wm * 128 + cl) * 32;      // + tm*1024 + p{ks}

    // B direct-global pointers (gate, lin)
    const u16* pBg = W + (size_t)(bcol + wn * 32 + cl) * H_DIM + kh * 8;
    const u16* pBl = W + (size_t)(I_DIM + bcol + wn * 32 + cl) * H_DIM + kh * 8;

    f32x16 acc[4][2] = {};   // [Mtile][gate=0 / lin=1]

#define G1_STAGE(k0, bs) do { \
    u16* S = lds + (bs) * 8192; \
    load_lds16(pA + (k0),                       S + dst); \
    load_lds16(pA + (size_t)128 * H_DIM + (k0), S + 4096 + dst); } while (0)
#define G1_LOADB(k0, B) do { \
    B[0] = *(const bf16x8*)(pBg + (k0));        \
    B[1] = *(const bf16x8*)(pBg + (k0) + 16);   \
    B[2] = *(const bf16x8*)(pBl + (k0));        \
    B[3] = *(const bf16x8*)(pBl + (k0) + 16);   } while (0)
#define G1_COMP(bcur, B) do { \
    const u16* L = lds + (bcur) * 8192 + rdA; \
    __builtin_amdgcn_s_setprio(1); \
    _Pragma("unroll") for (int ks = 0; ks < 2; ++ks) { \
        const int pk = ks ? p1 : p0; \
        _Pragma("unroll") for (int tm = 0; tm < 4; ++tm) { \
            bf16x8 af = *(const bf16x8*)(L + tm * 1024 + pk); \
            acc[tm][0] = __builtin_amdgcn_mfma_f32_32x32x16_bf16(af, B[ks],     acc[tm][0], 0, 0, 0); \
            acc[tm][1] = __builtin_amdgcn_mfma_f32_32x32x16_bf16(af, B[2 + ks], acc[tm][1], 0, 0, 0); \
        } } \
    __builtin_amdgcn_s_setprio(0); } while (0)

    bf16x8 b0[4], b1[4];
    // prologue: A(0)->buf0, A(1)->buf1, then B(0)
    G1_STAGE(0, 0);
    G1_STAGE(32, 1);
    __builtin_amdgcn_sched_barrier(0);
    G1_LOADB(0, b0);
    VMW(4); BAR();   // A(0),A(1) landed; B(0) in flight (reg-dep waits)

    int bc = 0;
#pragma unroll 1
    for (int i = 0; i < 16; ++i) {           // NT=32, 2 K-tiles per iter
        const bool w = (i < 15);
        // even t=2i: use b0, load b1
        if (w) G1_STAGE((2 * i + 2) * 32, (bc + 2 >= 3) ? bc - 1 : bc + 2);
        __builtin_amdgcn_sched_barrier(0);
        G1_LOADB((2 * i + 1) * 32, b1);
        G1_COMP(bc, b0);
        if (w) { VMW(6); }
        BAR();
        bc = (bc == 2) ? 0 : bc + 1;
        // odd t=2i+1: use b1, load b0
        if (w) {
            G1_STAGE((2 * i + 3) * 32, (bc + 2 >= 3) ? bc - 1 : bc + 2);
            __builtin_amdgcn_sched_barrier(0);
            G1_LOADB((2 * i + 2) * 32, b0);
        }
        G1_COMP(bc, b1);
        if (w) { VMW(6); BAR(); }
        bc = (bc == 2) ? 0 : bc + 1;
    }
#undef G1_STAGE
#undef G1_LOADB
#undef G1_COMP

    // epilogue: bias + gated gelu, bf16 store
    const int colg = bcol + wn * 32 + cl;
    const float bgv = bias[colg], blv = bias[I_DIM + colg];
#pragma unroll
    for (int tm = 0; tm < 4; ++tm) {
        const int rowb = brow + wm * 128 + tm * 32 + 4 * kh;
#pragma unroll
        for (int r = 0; r < 16; ++r) {
            const int row = rowb + (r & 3) + 8 * (r >> 2);
            float gate = acc[tm][0][r] + bgv;
            float lin  = acc[tm][1][r] + blv;
            hid[(size_t)row * I_DIM + colg] = f2bf(gelu_tanh(gate) * lin);
        }
    }
}

// =====================================================================
// GEMM2 (B-direct + 32x32x16): opb = hid·W2^T + b2 (bf16 out)
// Tile 256 x 128; 512 thr / 8 waves (4M x 2N); per-wave 64x64 =
// 2 Mtiles x 2 Ntiles. A: LDS ring-3 (48 KiB), B: direct global
// (grid (8,32): XCD = bid%8 = blockIdx.x -> one 1 MB B-panel per XCD,
// L2-resident). NT=128 -> 64 double-iters, same ledger as gemm1.
// =====================================================================
__global__ __launch_bounds__(512, 2) void gemm2_k(
    const u16* __restrict__ A, const u16* __restrict__ W,
    const float* __restrict__ bias, u16* __restrict__ opb)
{
    __shared__ u16 lds[3 * 8192];      // 48 KiB
    const int t = threadIdx.x;
    const int lane = t & 63, wid = t >> 6;
    const int wm = wid >> 1, wn = wid & 1;
    const int cl = lane & 31, kh = lane >> 5;

    const int brow = blockIdx.y * 256;
    const int bcol = blockIdx.x * 128;

    const int tr = t >> 2;
    const int sstg = ((tr >> 1) & 3) ^ ((tr >> 3) & 3);
    const int swz8 = ((t & 3) ^ sstg) * 8;
    const u16* pA = A + (size_t)(brow + tr) * I_DIM + swz8;
    const int dst = t * 8;

    const int s  = ((cl >> 1) & 3) ^ ((cl >> 3) & 3);
    const int p0 = ((0 + kh) ^ s) * 8;
    const int p1 = ((2 + kh) ^ s) * 8;
    const int rdA = (wm * 64 + cl) * 32;       // + tm*1024 + p{ks}

    const u16* pB0 = W + (size_t)(bcol + wn * 64 + cl) * I_DIM + kh * 8;
    const u16* pB1 = W + (size_t)(bcol + wn * 64 + 32 + cl) * I_DIM + kh * 8;

    f32x16 acc[2][2] = {};   // [Mtile][Ntile]

#define G2_STAGE(k0, bs) do { \
    u16* S = lds + (bs) * 8192; \
    load_lds16(pA + (k0),                       S + dst); \
    load_lds16(pA + (size_t)128 * I_DIM + (k0), S + 4096 + dst); } while (0)
#define G2_LOADB(k0, B) do { \
    B[0] = *(const bf16x8*)(pB0 + (k0));        \
    B[1] = *(const bf16x8*)(pB0 + (k0) + 16);   \
    B[2] = *(const bf16x8*)(pB1 + (k0));        \
    B[3] = *(const bf16x8*)(pB1 + (k0) + 16);   } while (0)
#define G2_COMP(bcur, B) do { \
    const u16* L = lds + (bcur) * 8192 + rdA; \
    __builtin_amdgcn_s_setprio(1); \
    _Pragma("unroll") for (int ks = 0; ks < 2; ++ks) { \
        const int pk = ks ? p1 : p0; \
        _Pragma("unroll") for (int tm = 0; tm < 2; ++tm) { \
            bf16x8 af = *(const bf16x8*)(L + tm * 1024 + pk); \
            acc[tm][0] = __builtin_amdgcn_mfma_f32_32x32x16_bf16(af, B[ks],     acc[tm][0], 0, 0, 0); \
            acc[tm][1] = __builtin_amdgcn_mfma_f32_32x32x16_bf16(af, B[2 + ks], acc[tm][1], 0, 0, 0); \
        } } \
    __builtin_amdgcn_s_setprio(0); } while (0)

    bf16x8 b0[4], b1[4];
    G2_STAGE(0, 0);
    G2_STAGE(32, 1);
    __builtin_amdgcn_sched_barrier(0);
    G2_LOADB(0, b0);
    VMW(4); BAR();

    int bc = 0;
#pragma unroll 1
    for (int i = 0; i < 64; ++i) {           // NT=128
        const bool w = (i < 63);
        if (w) G2_STAGE((2 * i + 2) * 32, (bc + 2 >= 3) ? bc - 1 : bc + 2);
        __builtin_amdgcn_sched_barrier(0);
        G2_LOADB((2 * i + 1) * 32, b1);
        G2_COMP(bc, b0);
        if (w) { VMW(6); }
        BAR();
        bc = (bc == 2) ? 0 : bc + 1;
        if (w) {
            G2_STAGE((2 * i + 3) * 32, (bc + 2 >= 3) ? bc - 1 : bc + 2);
            __builtin_amdgcn_sched_barrier(0);
            G2_LOADB((2 * i + 2) * 32, b0);
        }
        G2_COMP(bc, b1);
        if (w) { VMW(6); BAR(); }
        bc = (bc == 2) ? 0 : bc + 1;
    }
#undef G2_STAGE
#undef G2_LOADB
#undef G2_COMP

#pragma unroll
    for (int tn = 0; tn < 2; ++tn) {
        const int col = bcol + wn * 64 + tn * 32 + cl;
        const float bv = bias[col];
#pragma unroll
        for (int tm = 0; tm < 2; ++tm) {
            const int rowb = brow + wm * 64 + tm * 32 + 4 * kh;
#pragma unroll
            for (int r = 0; r < 16; ++r) {
                const int row = rowb + (r & 3) + 8 * (r >> 2);
                opb[(size_t)row * H_DIM + col] = f2bf(acc[tm][tn][r] + bv);
            }
        }
    }
}

// ---- block mean/var over one row of 1024 (256 threads x 4 elems) ----
__device__ __forceinline__ void block_mean_var(float s, float s2, float* red, int t,
                                               float& mu, float& var) {
#pragma unroll
    for (int off = 32; off > 0; off >>= 1) {
        s  += __shfl_down(s, off);
        s2 += __shfl_down(s2, off);
    }
    const int wid = t >> 6;
    if ((t & 63) == 0) { red[wid] = s; red[4 + wid] = s2; }
    __syncthreads();
    if (t == 0) {
        float a = red[0] + red[1] + red[2] + red[3];
        float b = red[4] + red[5] + red[6] + red[7];
        red[0] = a * (1.f / H_DIM);
        red[1] = b * (1.f / H_DIM);
    }
    __syncthreads();
    mu = red[0];
    var = red[1] - mu * mu;
}

// ---- fused prep: ln_pre (blocks 0..8191) + w1 cvt + w2 cvt ----
__global__ __launch_bounds__(256) void prep(
    const float* __restrict__ x, const float* __restrict__ lnw,
    const float* __restrict__ lnb, u16* __restrict__ xln,
    const float* __restrict__ w1, u16* __restrict__ w1b,
    const float* __restrict__ w2, u16* __restrict__ w2b)
{
    __shared__ float red[8];
    const int bid = blockIdx.x, t = threadIdx.x;
    if (bid < N_ROWS) {
        const float4 v = reinterpret_cast<const float4*>(x + (size_t)bid * H_DIM)[t];
        float mu, var;
        block_mean_var(v.x + v.y + v.z + v.w,
                       v.x * v.x + v.y * v.y + v.z * v.z + v.w * v.w, red, t, mu, var);
        const float rstd = rsqrtf(var + 1e-5f);
        const float4 wv = reinterpret_cast<const float4*>(lnw)[t];
        const float4 bv = reinterpret_cast<const float4*>(lnb)[t];
        u16x4 o;
        o.x = f2bf((v.x - mu) * rstd * wv.x + bv.x);
        o.y = f2bf((v.y - mu) * rstd * wv.y + bv.y);
        o.z = f2bf((v.z - mu) * rstd * wv.z + bv.z);
        o.w = f2bf((v.w - mu) * rstd * wv.w + bv.w);
        reinterpret_cast<u16x4*>(xln + (size_t)bid * H_DIM)[t] = o;
    } else if (bid < N_ROWS + 8192) {
        const int i = (bid - N_ROWS) * 256 + t;
        const float4 v = reinterpret_cast<const float4*>(w1)[i];
        u16x4 o = { f2bf(v.x), f2bf(v.y), f2bf(v.z), f2bf(v.w) };
        reinterpret_cast<u16x4*>(w1b)[i] = o;
    } else {
        const int i = (bid - N_ROWS - 8192) * 256 + t;
        const float4 v = reinterpret_cast<const float4*>(w2)[i];
        u16x4 o = { f2bf(v.x), f2bf(v.y), f2bf(v.z), f2bf(v.w) };
        reinterpret_cast<u16x4*>(w2b)[i] = o;
    }
}

// post-LN over bf16 'op' rows + fp32 residual add
__global__ void ln_post_res(const u16* __restrict__ op, const float* __restrict__ w,
                            const float* __restrict__ b, const float* __restrict__ x,
                            float* __restrict__ out)
{
    __shared__ float red[8];
    const int row = blockIdx.x, t = threadIdx.x;
    const u16x4 hv = reinterpret_cast<const u16x4*>(op + (size_t)row * H_DIM)[t];
    float4 v;
    v.x = bf2f(hv.x); v.y = bf2f(hv.y); v.z = bf2f(hv.z); v.w = bf2f(hv.w);
    float mu, var;
    block_mean_var(v.x + v.y + v.z + v.w,
                   v.x * v.x + v.y * v.y + v.z * v.z + v.w * v.w, red, t, mu, var);
    const float rstd = rsqrtf(var + 1e-5f);
    const float4 wv = reinterpret_cast<const float4*>(w)[t];
    const float4 bv = reinterpret_cast<const float4*>(b)[t];
    const float4 xv = reinterpret_cast<const float4*>(x + (size_t)row * H_DIM)[t];
    float4 o;
    o.x = (v.x - mu) * rstd * wv.x + bv.x + xv.x;
    o.y = (v.y - mu) * rstd * wv.y + bv.y + xv.y;
    o.z = (v.z - mu) * rstd * wv.z + bv.z + xv.z;
    o.w = (v.w - mu) * rstd * wv.w + bv.w + xv.w;
    reinterpret_cast<float4*>(out + (size_t)row * H_DIM)[t] = o;
}

extern "C" void kernel_launch(void* const* d_in, const int* in_sizes, int n_in,
                              void* d_out, int out_size, void* d_ws, size_t ws_size,
                              hipStream_t stream)
{
    const float* x   = (const float*)d_in[0];
    const float* lnw = (const float*)d_in[1];
    const float* lnb = (const float*)d_in[2];
    const float* w1  = (const float*)d_in[3];
    const float* b1  = (const float*)d_in[4];
    const float* w2  = (const float*)d_in[5];
    const float* b2  = (const float*)d_in[6];
    const float* pw  = (const float*)d_in[7];
    const float* pb  = (const float*)d_in[8];
    float* out = (float*)d_out;

    // Workspace layout (104 MiB peak; proven r7-r9):
    //   xln [0,16M) | w1b [16,32M) | hid [32,96M) | w2b [96,104M)
    //   opb over dead xln [0,16M) after gemm1.
    char* ws = (char*)d_ws;
    u16* xln = (u16*)(ws);
    u16* w1b = (u16*)(ws + (16u << 20));
    u16* hid = (u16*)(ws + (32u << 20));
    u16* w2b = (u16*)(ws + (96u << 20));
    u16* opb = (u16*)(ws);

    prep<<<20480, 256, 0, stream>>>(x, lnw, lnb, xln, w1, w1b, w2, w2b);
    gemm1_gated<<<dim3(I_DIM / 128, N_ROWS / 256), 512, 0, stream>>>(xln, w1b, b1, hid);
    gemm2_k<<<dim3(H_DIM / 128, N_ROWS / 256), 512, 0, stream>>>(hid, w2b, b2, opb);
    ln_post_res<<<N_ROWS, 256, 0, stream>>>(opb, pw, pb, x, out);
}

// Round 11
// 266.433 us; speedup vs baseline: 1.5638x; 1.5638x over previous
//
#include <hip/hip_runtime.h>
#include <stdint.h>

#define N_ROWS 8192
#define H_DIM  1024
#define I_DIM  4096

typedef unsigned short u16;
typedef __bf16 bf16x8 __attribute__((ext_vector_type(8)));
typedef float f32x4 __attribute__((ext_vector_type(4)));
typedef u16 u16x4 __attribute__((ext_vector_type(4)));

#define BAR()   asm volatile("s_barrier" ::: "memory")
#define LGKM0() asm volatile("s_waitcnt lgkmcnt(0)" ::: "memory")
#define VMW(n)  asm volatile("s_waitcnt vmcnt(" #n ")" ::: "memory")

__device__ __forceinline__ u16 f2bf(float f) {
    union { float f; uint32_t u; } v; v.f = f;
    uint32_t u = v.u;
    u += 0x7FFFu + ((u >> 16) & 1u);   // RNE
    return (u16)(u >> 16);
}

__device__ __forceinline__ float bf2f(u16 h) {
    union { uint32_t u; float f; } v; v.u = ((uint32_t)h) << 16;
    return v.f;
}

__device__ __forceinline__ float gelu_tanh(float x) {
    float u = 0.7978845608028654f * (x + 0.044715f * x * x * x);
    u = fminf(fmaxf(u, -15.f), 15.f);
    float e = __expf(2.f * u);
    float t = (e - 1.f) / (e + 1.f);
    return 0.5f * x * (1.f + t);
}

// ---- global -> LDS direct (16B per lane) ----
__device__ __forceinline__ void load_lds16(const void* g, void* l) {
    auto gp = reinterpret_cast<const __attribute__((address_space(1))) uint32_t*>(
        reinterpret_cast<uintptr_t>(g));
    auto lp = reinterpret_cast<__attribute__((address_space(3))) uint32_t*>(
        static_cast<uint32_t>(reinterpret_cast<uintptr_t>(l)));
    __builtin_amdgcn_global_load_lds(gp, lp, 16, 0, 0);
}

// =====================================================================
// GEMM1 (r8 exact — session-best 153 us, MfmaUtil 41, conflicts 0):
// hid = gelu(xln·W1g^T+bg)*(xln·W1l^T+bl), bf16 out.
// Tile 128 rows x 128 hid-cols; 512 thr / 8 waves (2M x 4N); per-wave
// 64 rows x 32 hid x {gate,lin}. BK=32; LDS ring-3 x 24 KiB = 72 KiB
// -> 2 blocks/CU = 16 waves (TLP; occupancy 39% measured r8).
// Per kt: stage tile kt+2 (3 loads/thr); 8 ds_read; 16 MFMA; VMW(3); BAR.
// swizzle: k-granule ^ ((row>>1)&3) (measured 0-conflict, r4-r9).
// =====================================================================
__global__ __launch_bounds__(512, 4) void gemm1_gated(
    const u16* __restrict__ A, const u16* __restrict__ W,
    const float* __restrict__ bias, u16* __restrict__ hid)
{
    __shared__ u16 lds[3 * 12288];     // 72 KiB
    const int t = threadIdx.x;
    const int lane = t & 63, wid = t >> 6;
    const int wm = wid >> 2, wn = wid & 3;
    const int g = lane >> 4, r16 = lane & 15;

    const int brow = blockIdx.y * 128;
    const int bcol = blockIdx.x * 128;

    const int tr = t >> 2;
    const int swz8 = ((t & 3) ^ ((tr >> 1) & 3)) * 8;
    const u16* pA  = A + (size_t)(brow + tr) * H_DIM + swz8;
    const u16* pBg = W + (size_t)(bcol + tr) * H_DIM + swz8;           // gate col
    const u16* pBl = W + (size_t)(I_DIM + bcol + tr) * H_DIM + swz8;   // lin col
    const int dst = t * 8;

    const int sl  = (g ^ ((r16 >> 1) & 3)) * 8;
    const int rdA = (wm * 64 + r16) * 32 + sl;             // + m*512
    const int rdB = 4096 + (wn * 32 + r16) * 32 + sl;      // + n*512; lin +4096

    f32x4 accg[4][2] = {};
    f32x4 accl[4][2] = {};

#define STG1(S, k0) do { \
    load_lds16(pA  + (k0), (S) + dst); \
    load_lds16(pBg + (k0), (S) + 4096 + dst); \
    load_lds16(pBl + (k0), (S) + 8192 + dst); } while (0)

    STG1(lds, 0);
    STG1(lds + 12288, 32);
    VMW(3); BAR();

    const int NT = H_DIM / 32;   // 32
    int bc = 0;
#pragma unroll 1
    for (int kt = 0; kt < NT; ++kt) {
        const u16* L = lds + bc * 12288;
        if (kt + 2 < NT) {
            u16* S = lds + ((bc + 2 >= 3) ? (bc - 1) : (bc + 2)) * 12288;
            STG1(S, (kt + 2) * 32);
        }
        bf16x8 af[4], bg[2], bl[2];
#pragma unroll
        for (int m = 0; m < 4; ++m) af[m] = *(const bf16x8*)(L + rdA + m * 512);
#pragma unroll
        for (int n = 0; n < 2; ++n) {
            bg[n] = *(const bf16x8*)(L + rdB + n * 512);
            bl[n] = *(const bf16x8*)(L + rdB + 4096 + n * 512);
        }
        __builtin_amdgcn_s_setprio(1);
#pragma unroll
        for (int m = 0; m < 4; ++m)
#pragma unroll
            for (int n = 0; n < 2; ++n) {
                accg[m][n] = __builtin_amdgcn_mfma_f32_16x16x32_bf16(af[m], bg[n], accg[m][n], 0, 0, 0);
                accl[m][n] = __builtin_amdgcn_mfma_f32_16x16x32_bf16(af[m], bl[n], accl[m][n], 0, 0, 0);
            }
        __builtin_amdgcn_s_setprio(0);
        if (kt + 2 < NT) { VMW(3); } else { VMW(0); }
        BAR();
        bc = (bc == 2) ? 0 : bc + 1;
    }
#undef STG1

#pragma unroll
    for (int n = 0; n < 2; ++n) {
        const int cg = bcol + wn * 32 + n * 16 + r16;
        const float bgv = bias[cg], blv = bias[I_DIM + cg];
#pragma unroll
        for (int m = 0; m < 4; ++m) {
            const int row = brow + wm * 64 + m * 16 + g * 4;
            u16* hp = hid + (size_t)row * I_DIM + cg;
#pragma unroll
            for (int r = 0; r < 4; ++r) {
                float gate = accg[m][n][r] + bgv;
                float lin  = accl[m][n][r] + blv;
                hp[(size_t)r * I_DIM] = f2bf(gelu_tanh(gate) * lin);
            }
        }
    }
}

// =====================================================================
// GEMM2 (r7 exact — session-best ~74 us): opb = hid·W2^T + b2 (bf16).
// Tile 256 x 128; 8 waves (4M x 2N); per-wave 64x64; BK=64 (2 ks).
// LDS: 2 bufs x 48 KiB; A-ks0@0, A-ks1@8192 (256x32), B-ks0@16384,
// B-ks1@20480 (128x32). 4 phases/iter x 16 MFMA; VMW(6) every phase end.
// =====================================================================
__global__ __launch_bounds__(512, 2) void gemm2_k(
    const u16* __restrict__ A, const u16* __restrict__ W,
    const float* __restrict__ bias, u16* __restrict__ opb)
{
    __shared__ u16 lds[2 * 24576];     // 96 KiB
    const int t = threadIdx.x;
    const int lane = t & 63, wid = t >> 6;
    const int wm = wid >> 1, wn = wid & 1;
    const int g = lane >> 4, r16 = lane & 15;

    const int brow = blockIdx.y * 256;
    const int bcol = blockIdx.x * 128;

    const int tr = t >> 2;
    const int swz8 = ((t & 3) ^ ((tr >> 1) & 3)) * 8;
    const u16* pA = A + (size_t)(brow + tr) * I_DIM + swz8;
    const u16* pB = W + (size_t)(bcol + tr) * I_DIM + swz8;
    const int dst = t * 8;

    const int sl  = (g ^ ((r16 >> 1) & 3)) * 8;
    const int rdA = (wm * 64 + r16) * 32 + sl;            // + ks*8192 + m*512
    const int rdB = 16384 + (wn * 64 + r16) * 32 + sl;    // + ks*4096 + n*512

    f32x4 acc[4][4] = {};

    u16* const B0 = lds;
    u16* const B1 = lds + 24576;

#define STG_A2(S, kk, ks) do { \
    load_lds16(pA + (kk) + (ks) * 32,                       (S) + (ks) * 8192 + dst); \
    load_lds16(pA + (size_t)128 * I_DIM + (kk) + (ks) * 32, (S) + (ks) * 8192 + 4096 + dst); } while (0)
#define STG_B2(S, kk, ks) do { \
    load_lds16(pB + (kk) + (ks) * 32, (S) + 16384 + (ks) * 4096 + dst); } while (0)
#define RD2(L, ks) { _Pragma("unroll") for (int m = 0; m < 4; ++m) \
    af[m] = *(const bf16x8*)((L) + (ks) * 8192 + rdA + m * 512); \
    _Pragma("unroll") for (int n = 0; n < 4; ++n) \
    bf[n] = *(const bf16x8*)((L) + (ks) * 4096 + rdB + n * 512); }
#define MM2() { _Pragma("unroll") for (int m = 0; m < 4; ++m) _Pragma("unroll") for (int n = 0; n < 4; ++n) \
    acc[m][n] = __builtin_amdgcn_mfma_f32_16x16x32_bf16(af[m], bf[n], acc[m][n], 0, 0, 0); }

    // prologue groups: G1=t0ks0, G2=t0ks1, G3=t1ks0 (3 loads each)
    STG_A2(B0, 0, 0); STG_B2(B0, 0, 0);
    STG_A2(B0, 0, 1); STG_B2(B0, 0, 1);
    STG_A2(B1, 64, 0); STG_B2(B1, 64, 0);
    VMW(6); BAR();   // G1 landed; G2,G3 in flight

    const int NI = I_DIM / 128;   // 32 iterations
#pragma unroll 1
    for (int it = 0; it < NI; ++it) {
        const int kkO  = (2 * it + 1) * 64;
        const int kkE2 = (2 * it + 2) * 64;
        const int kkO2 = (2 * it + 3) * 64;
        const bool s2 = (it + 1 < NI);
        const bool last = (it == NI - 1);
        bf16x8 af[4], bf[4];

        // Ph1: stage B1ks1(O); compute buf0 ks0
        STG_A2(B1, kkO, 1); STG_B2(B1, kkO, 1);
        RD2(B0, 0);
        BAR(); LGKM0();
        __builtin_amdgcn_s_setprio(1); MM2(); __builtin_amdgcn_s_setprio(0);
        VMW(6);
        BAR();

        // Ph2: stage B0ks0(E+2); compute buf0 ks1
        if (s2) { STG_A2(B0, kkE2, 0); STG_B2(B0, kkE2, 0); }
        RD2(B0, 1);
        BAR(); LGKM0();
        __builtin_amdgcn_s_setprio(1); MM2(); __builtin_amdgcn_s_setprio(0);
        if (last) { VMW(3); } else { VMW(6); }
        BAR();

        // Ph3: stage B0ks1(E+2); compute buf1 ks0
        if (s2) { STG_A2(B0, kkE2, 1); STG_B2(B0, kkE2, 1); }
        RD2(B1, 0);
        BAR(); LGKM0();
        __builtin_amdgcn_s_setprio(1); MM2(); __builtin_amdgcn_s_setprio(0);
        if (last) { VMW(0); } else { VMW(6); }
        BAR();

        // Ph4: stage B1ks0(O+2); compute buf1 ks1
        if (s2) { STG_A2(B1, kkO2, 0); STG_B2(B1, kkO2, 0); }
        RD2(B1, 1);
        BAR(); LGKM0();
        __builtin_amdgcn_s_setprio(1); MM2(); __builtin_amdgcn_s_setprio(0);
        if (!last) { VMW(6); }
        BAR();
    }
#undef STG_A2
#undef STG_B2
#undef RD2
#undef MM2

#pragma unroll
    for (int n = 0; n < 4; ++n) {
        const int cg = bcol + wn * 64 + n * 16 + r16;
        const float bv = bias[cg];
#pragma unroll
        for (int m = 0; m < 4; ++m) {
            const int row = brow + wm * 64 + m * 16 + g * 4;
            u16* op = opb + (size_t)row * H_DIM + cg;
#pragma unroll
            for (int r = 0; r < 4; ++r)
                op[(size_t)r * H_DIM] = f2bf(acc[m][n][r] + bv);
        }
    }
}

// ---- block mean/var over one row of 1024 (256 threads x 4 elems) ----
__device__ __forceinline__ void block_mean_var(float s, float s2, float* red, int t,
                                               float& mu, float& var) {
#pragma unroll
    for (int off = 32; off > 0; off >>= 1) {
        s  += __shfl_down(s, off);
        s2 += __shfl_down(s2, off);
    }
    const int wid = t >> 6;
    if ((t & 63) == 0) { red[wid] = s; red[4 + wid] = s2; }
    __syncthreads();
    if (t == 0) {
        float a = red[0] + red[1] + red[2] + red[3];
        float b = red[4] + red[5] + red[6] + red[7];
        red[0] = a * (1.f / H_DIM);
        red[1] = b * (1.f / H_DIM);
    }
    __syncthreads();
    mu = red[0];
    var = red[1] - mu * mu;
}

// ---- fused prep: ln_pre (blocks 0..8191) + w1 cvt + w2 cvt ----
__global__ __launch_bounds__(256) void prep(
    const float* __restrict__ x, const float* __restrict__ lnw,
    const float* __restrict__ lnb, u16* __restrict__ xln,
    const float* __restrict__ w1, u16* __restrict__ w1b,
    const float* __restrict__ w2, u16* __restrict__ w2b)
{
    __shared__ float red[8];
    const int bid = blockIdx.x, t = threadIdx.x;
    if (bid < N_ROWS) {
        const float4 v = reinterpret_cast<const float4*>(x + (size_t)bid * H_DIM)[t];
        float mu, var;
        block_mean_var(v.x + v.y + v.z + v.w,
                       v.x * v.x + v.y * v.y + v.z * v.z + v.w * v.w, red, t, mu, var);
        const float rstd = rsqrtf(var + 1e-5f);
        const float4 wv = reinterpret_cast<const float4*>(lnw)[t];
        const float4 bv = reinterpret_cast<const float4*>(lnb)[t];
        u16x4 o;
        o.x = f2bf((v.x - mu) * rstd * wv.x + bv.x);
        o.y = f2bf((v.y - mu) * rstd * wv.y + bv.y);
        o.z = f2bf((v.z - mu) * rstd * wv.z + bv.z);
        o.w = f2bf((v.w - mu) * rstd * wv.w + bv.w);
        reinterpret_cast<u16x4*>(xln + (size_t)bid * H_DIM)[t] = o;
    } else if (bid < N_ROWS + 8192) {
        const int i = (bid - N_ROWS) * 256 + t;
        const float4 v = reinterpret_cast<const float4*>(w1)[i];
        u16x4 o = { f2bf(v.x), f2bf(v.y), f2bf(v.z), f2bf(v.w) };
        reinterpret_cast<u16x4*>(w1b)[i] = o;
    } else {
        const int i = (bid - N_ROWS - 8192) * 256 + t;
        const float4 v = reinterpret_cast<const float4*>(w2)[i];
        u16x4 o = { f2bf(v.x), f2bf(v.y), f2bf(v.z), f2bf(v.w) };
        reinterpret_cast<u16x4*>(w2b)[i] = o;
    }
}

// post-LN over bf16 'op' rows + fp32 residual add
__global__ void ln_post_res(const u16* __restrict__ op, const float* __restrict__ w,
                            const float* __restrict__ b, const float* __restrict__ x,
                            float* __restrict__ out)
{
    __shared__ float red[8];
    const int row = blockIdx.x, t = threadIdx.x;
    const u16x4 hv = reinterpret_cast<const u16x4*>(op + (size_t)row * H_DIM)[t];
    float4 v;
    v.x = bf2f(hv.x); v.y = bf2f(hv.y); v.z = bf2f(hv.z); v.w = bf2f(hv.w);
    float mu, var;
    block_mean_var(v.x + v.y + v.z + v.w,
                   v.x * v.x + v.y * v.y + v.z * v.z + v.w * v.w, red, t, mu, var);
    const float rstd = rsqrtf(var + 1e-5f);
    const float4 wv = reinterpret_cast<const float4*>(w)[t];
    const float4 bv = reinterpret_cast<const float4*>(b)[t];
    const float4 xv = reinterpret_cast<const float4*>(x + (size_t)row * H_DIM)[t];
    float4 o;
    o.x = (v.x - mu) * rstd * wv.x + bv.x + xv.x;
    o.y = (v.y - mu) * rstd * wv.y + bv.y + xv.y;
    o.z = (v.z - mu) * rstd * wv.z + bv.z + xv.z;
    o.w = (v.w - mu) * rstd * wv.w + bv.w + xv.w;
    reinterpret_cast<float4*>(out + (size_t)row * H_DIM)[t] = o;
}

extern "C" void kernel_launch(void* const* d_in, const int* in_sizes, int n_in,
                              void* d_out, int out_size, void* d_ws, size_t ws_size,
                              hipStream_t stream)
{
    const float* x   = (const float*)d_in[0];
    const float* lnw = (const float*)d_in[1];
    const float* lnb = (const float*)d_in[2];
    const float* w1  = (const float*)d_in[3];
    const float* b1  = (const float*)d_in[4];
    const float* w2  = (const float*)d_in[5];
    const float* b2  = (const float*)d_in[6];
    const float* pw  = (const float*)d_in[7];
    const float* pb  = (const float*)d_in[8];
    float* out = (float*)d_out;

    // Workspace layout (104 MiB peak; proven r7-r10):
    //   xln [0,16M) | w1b [16,32M) | hid [32,96M) | w2b [96,104M)
    //   opb over dead xln [0,16M) after gemm1.
    char* ws = (char*)d_ws;
    u16* xln = (u16*)(ws);
    u16* w1b = (u16*)(ws + (16u << 20));
    u16* hid = (u16*)(ws + (32u << 20));
    u16* w2b = (u16*)(ws + (96u << 20));
    u16* opb = (u16*)(ws);

    prep<<<20480, 256, 0, stream>>>(x, lnw, lnb, xln, w1, w1b, w2, w2b);
    gemm1_gated<<<dim3(I_DIM / 128, N_ROWS / 128), 512, 0, stream>>>(xln, w1b, b1, hid);
    gemm2_k<<<dim3(H_DIM / 128, N_ROWS / 256), 512, 0, stream>>>(hid, w2b, b2, opb);
    ln_post_res<<<N_ROWS, 256, 0, stream>>>(opb, pw, pb, x, out);
}

// Round 12
// 265.318 us; speedup vs baseline: 1.5704x; 1.0042x over previous
//
#include <hip/hip_runtime.h>
#include <stdint.h>

#define N_ROWS 8192
#define H_DIM  1024
#define I_DIM  4096

typedef unsigned short u16;
typedef __bf16 bf16x8 __attribute__((ext_vector_type(8)));
typedef float f32x4 __attribute__((ext_vector_type(4)));
typedef u16 u16x4 __attribute__((ext_vector_type(4)));

#define BAR()   asm volatile("s_barrier" ::: "memory")
#define LGKM0() asm volatile("s_waitcnt lgkmcnt(0)" ::: "memory")
#define VMW(n)  asm volatile("s_waitcnt vmcnt(" #n ")" ::: "memory")

__device__ __forceinline__ u16 f2bf(float f) {
    union { float f; uint32_t u; } v; v.f = f;
    uint32_t u = v.u;
    u += 0x7FFFu + ((u >> 16) & 1u);   // RNE
    return (u16)(u >> 16);
}

__device__ __forceinline__ float bf2f(u16 h) {
    union { uint32_t u; float f; } v; v.u = ((uint32_t)h) << 16;
    return v.f;
}

__device__ __forceinline__ float gelu_tanh(float x) {
    float u = 0.7978845608028654f * (x + 0.044715f * x * x * x);
    u = fminf(fmaxf(u, -15.f), 15.f);
    float e = __expf(2.f * u);
    float t = (e - 1.f) / (e + 1.f);
    return 0.5f * x * (1.f + t);
}

// ---- global -> LDS direct (16B per lane) ----
__device__ __forceinline__ void load_lds16(const void* g, void* l) {
    auto gp = reinterpret_cast<const __attribute__((address_space(1))) uint32_t*>(
        reinterpret_cast<uintptr_t>(g));
    auto lp = reinterpret_cast<__attribute__((address_space(3))) uint32_t*>(
        static_cast<uint32_t>(reinterpret_cast<uintptr_t>(l)));
    __builtin_amdgcn_global_load_lds(gp, lp, 16, 0, 0);
}

// =====================================================================
// GEMM1 (r8/r11 exact — session-best 153 us, MfmaUtil 41, conflicts 0):
// hid = gelu(xln·W1g^T+bg)*(xln·W1l^T+bl), bf16 out.
// Tile 128 rows x 128 hid-cols; 512 thr / 8 waves (2M x 4N); per-wave
// 64 rows x 32 hid x {gate,lin}. BK=32; LDS ring-3 x 24 KiB = 72 KiB
// -> 2 blocks/CU = 16 waves. Per kt: stage kt+2 (3 loads/thr);
// 8 ds_read; 16 MFMA; VMW(3); BAR.
// swizzle: k-granule ^ ((row>>1)&3) (measured 0-conflict, r4-r11).
// =====================================================================
__global__ __launch_bounds__(512, 4) void gemm1_gated(
    const u16* __restrict__ A, const u16* __restrict__ W,
    const float* __restrict__ bias, u16* __restrict__ hid)
{
    __shared__ u16 lds[3 * 12288];     // 72 KiB
    const int t = threadIdx.x;
    const int lane = t & 63, wid = t >> 6;
    const int wm = wid >> 2, wn = wid & 3;
    const int g = lane >> 4, r16 = lane & 15;

    const int brow = blockIdx.y * 128;
    const int bcol = blockIdx.x * 128;

    const int tr = t >> 2;
    const int swz8 = ((t & 3) ^ ((tr >> 1) & 3)) * 8;
    const u16* pA  = A + (size_t)(brow + tr) * H_DIM + swz8;
    const u16* pBg = W + (size_t)(bcol + tr) * H_DIM + swz8;           // gate col
    const u16* pBl = W + (size_t)(I_DIM + bcol + tr) * H_DIM + swz8;   // lin col
    const int dst = t * 8;

    const int sl  = (g ^ ((r16 >> 1) & 3)) * 8;
    const int rdA = (wm * 64 + r16) * 32 + sl;             // + m*512
    const int rdB = 4096 + (wn * 32 + r16) * 32 + sl;      // + n*512; lin +4096

    f32x4 accg[4][2] = {};
    f32x4 accl[4][2] = {};

#define STG1(S, k0) do { \
    load_lds16(pA  + (k0), (S) + dst); \
    load_lds16(pBg + (k0), (S) + 4096 + dst); \
    load_lds16(pBl + (k0), (S) + 8192 + dst); } while (0)

    STG1(lds, 0);
    STG1(lds + 12288, 32);
    VMW(3); BAR();

    const int NT = H_DIM / 32;   // 32
    int bc = 0;
#pragma unroll 1
    for (int kt = 0; kt < NT; ++kt) {
        const u16* L = lds + bc * 12288;
        if (kt + 2 < NT) {
            u16* S = lds + ((bc + 2 >= 3) ? (bc - 1) : (bc + 2)) * 12288;
            STG1(S, (kt + 2) * 32);
        }
        bf16x8 af[4], bg[2], bl[2];
#pragma unroll
        for (int m = 0; m < 4; ++m) af[m] = *(const bf16x8*)(L + rdA + m * 512);
#pragma unroll
        for (int n = 0; n < 2; ++n) {
            bg[n] = *(const bf16x8*)(L + rdB + n * 512);
            bl[n] = *(const bf16x8*)(L + rdB + 4096 + n * 512);
        }
        __builtin_amdgcn_s_setprio(1);
#pragma unroll
        for (int m = 0; m < 4; ++m)
#pragma unroll
            for (int n = 0; n < 2; ++n) {
                accg[m][n] = __builtin_amdgcn_mfma_f32_16x16x32_bf16(af[m], bg[n], accg[m][n], 0, 0, 0);
                accl[m][n] = __builtin_amdgcn_mfma_f32_16x16x32_bf16(af[m], bl[n], accl[m][n], 0, 0, 0);
            }
        __builtin_amdgcn_s_setprio(0);
        if (kt + 2 < NT) { VMW(3); } else { VMW(0); }
        BAR();
        bc = (bc == 2) ? 0 : bc + 1;
    }
#undef STG1

#pragma unroll
    for (int n = 0; n < 2; ++n) {
        const int cg = bcol + wn * 32 + n * 16 + r16;
        const float bgv = bias[cg], blv = bias[I_DIM + cg];
#pragma unroll
        for (int m = 0; m < 4; ++m) {
            const int row = brow + wm * 64 + m * 16 + g * 4;
            u16* hp = hid + (size_t)row * I_DIM + cg;
#pragma unroll
            for (int r = 0; r < 4; ++r) {
                float gate = accg[m][n][r] + bgv;
                float lin  = accl[m][n][r] + blv;
                hp[(size_t)r * I_DIM] = f2bf(gelu_tanh(gate) * lin);
            }
        }
    }
}

// =====================================================================
// GEMM2 (r7/r11 exact — session-best ~74 us): opb = hid·W2^T + b2 (bf16).
// Tile 256 x 128; 8 waves (4M x 2N); per-wave 64x64; BK=64 (2 ks).
// LDS: 2 bufs x 48 KiB. 4 phases/iter x 16 MFMA; VMW(6) every phase end.
// =====================================================================
__global__ __launch_bounds__(512, 2) void gemm2_k(
    const u16* __restrict__ A, const u16* __restrict__ W,
    const float* __restrict__ bias, u16* __restrict__ opb)
{
    __shared__ u16 lds[2 * 24576];     // 96 KiB
    const int t = threadIdx.x;
    const int lane = t & 63, wid = t >> 6;
    const int wm = wid >> 1, wn = wid & 1;
    const int g = lane >> 4, r16 = lane & 15;

    const int brow = blockIdx.y * 256;
    const int bcol = blockIdx.x * 128;

    const int tr = t >> 2;
    const int swz8 = ((t & 3) ^ ((tr >> 1) & 3)) * 8;
    const u16* pA = A + (size_t)(brow + tr) * I_DIM + swz8;
    const u16* pB = W + (size_t)(bcol + tr) * I_DIM + swz8;
    const int dst = t * 8;

    const int sl  = (g ^ ((r16 >> 1) & 3)) * 8;
    const int rdA = (wm * 64 + r16) * 32 + sl;            // + ks*8192 + m*512
    const int rdB = 16384 + (wn * 64 + r16) * 32 + sl;    // + ks*4096 + n*512

    f32x4 acc[4][4] = {};

    u16* const B0 = lds;
    u16* const B1 = lds + 24576;

#define STG_A2(S, kk, ks) do { \
    load_lds16(pA + (kk) + (ks) * 32,                       (S) + (ks) * 8192 + dst); \
    load_lds16(pA + (size_t)128 * I_DIM + (kk) + (ks) * 32, (S) + (ks) * 8192 + 4096 + dst); } while (0)
#define STG_B2(S, kk, ks) do { \
    load_lds16(pB + (kk) + (ks) * 32, (S) + 16384 + (ks) * 4096 + dst); } while (0)
#define RD2(L, ks) { _Pragma("unroll") for (int m = 0; m < 4; ++m) \
    af[m] = *(const bf16x8*)((L) + (ks) * 8192 + rdA + m * 512); \
    _Pragma("unroll") for (int n = 0; n < 4; ++n) \
    bf[n] = *(const bf16x8*)((L) + (ks) * 4096 + rdB + n * 512); }
#define MM2() { _Pragma("unroll") for (int m = 0; m < 4; ++m) _Pragma("unroll") for (int n = 0; n < 4; ++n) \
    acc[m][n] = __builtin_amdgcn_mfma_f32_16x16x32_bf16(af[m], bf[n], acc[m][n], 0, 0, 0); }

    STG_A2(B0, 0, 0); STG_B2(B0, 0, 0);
    STG_A2(B0, 0, 1); STG_B2(B0, 0, 1);
    STG_A2(B1, 64, 0); STG_B2(B1, 64, 0);
    VMW(6); BAR();   // G1 landed; G2,G3 in flight

    const int NI = I_DIM / 128;   // 32 iterations
#pragma unroll 1
    for (int it = 0; it < NI; ++it) {
        const int kkO  = (2 * it + 1) * 64;
        const int kkE2 = (2 * it + 2) * 64;
        const int kkO2 = (2 * it + 3) * 64;
        const bool s2 = (it + 1 < NI);
        const bool last = (it == NI - 1);
        bf16x8 af[4], bf[4];

        STG_A2(B1, kkO, 1); STG_B2(B1, kkO, 1);
        RD2(B0, 0);
        BAR(); LGKM0();
        __builtin_amdgcn_s_setprio(1); MM2(); __builtin_amdgcn_s_setprio(0);
        VMW(6);
        BAR();

        if (s2) { STG_A2(B0, kkE2, 0); STG_B2(B0, kkE2, 0); }
        RD2(B0, 1);
        BAR(); LGKM0();
        __builtin_amdgcn_s_setprio(1); MM2(); __builtin_amdgcn_s_setprio(0);
        if (last) { VMW(3); } else { VMW(6); }
        BAR();

        if (s2) { STG_A2(B0, kkE2, 1); STG_B2(B0, kkE2, 1); }
        RD2(B1, 0);
        BAR(); LGKM0();
        __builtin_amdgcn_s_setprio(1); MM2(); __builtin_amdgcn_s_setprio(0);
        if (last) { VMW(0); } else { VMW(6); }
        BAR();

        if (s2) { STG_A2(B1, kkO2, 0); STG_B2(B1, kkO2, 0); }
        RD2(B1, 1);
        BAR(); LGKM0();
        __builtin_amdgcn_s_setprio(1); MM2(); __builtin_amdgcn_s_setprio(0);
        if (!last) { VMW(6); }
        BAR();
    }
#undef STG_A2
#undef STG_B2
#undef RD2
#undef MM2

#pragma unroll
    for (int n = 0; n < 4; ++n) {
        const int cg = bcol + wn * 64 + n * 16 + r16;
        const float bv = bias[cg];
#pragma unroll
        for (int m = 0; m < 4; ++m) {
            const int row = brow + wm * 64 + m * 16 + g * 4;
            u16* op = opb + (size_t)row * H_DIM + cg;
#pragma unroll
            for (int r = 0; r < 4; ++r)
                op[(size_t)r * H_DIM] = f2bf(acc[m][n][r] + bv);
        }
    }
}

// =====================================================================
// prep2: wave-per-row pre-LN (blocks 0..2047, 4 rows each, shfl-only
// reduction — no LDS/syncthreads) + grid-stride weight cvt (2048..4095).
// =====================================================================
__global__ __launch_bounds__(256) void prep2(
    const float* __restrict__ x, const float* __restrict__ lnw,
    const float* __restrict__ lnb, u16* __restrict__ xln,
    const float* __restrict__ w1, u16* __restrict__ w1b,
    const float* __restrict__ w2, u16* __restrict__ w2b)
{
    const int bid = blockIdx.x, t = threadIdx.x;
    if (bid < 2048) {
        const int lane = t & 63, w = t >> 6;
        const int row = bid * 4 + w;
        const float4* xr = reinterpret_cast<const float4*>(x + (size_t)row * H_DIM);
        float4 v[4];
        float s = 0.f, s2 = 0.f;
#pragma unroll
        for (int i = 0; i < 4; ++i) {
            v[i] = xr[lane + i * 64];
            s  += v[i].x + v[i].y + v[i].z + v[i].w;
            s2 += v[i].x * v[i].x + v[i].y * v[i].y + v[i].z * v[i].z + v[i].w * v[i].w;
        }
#pragma unroll
        for (int off = 32; off > 0; off >>= 1) {
            s  += __shfl_xor(s, off);
            s2 += __shfl_xor(s2, off);
        }
        const float mu = s * (1.f / H_DIM);
        const float var = s2 * (1.f / H_DIM) - mu * mu;
        const float rstd = rsqrtf(var + 1e-5f);
        u16x4* xo = reinterpret_cast<u16x4*>(xln + (size_t)row * H_DIM);
#pragma unroll
        for (int i = 0; i < 4; ++i) {
            const float4 wv = reinterpret_cast<const float4*>(lnw)[lane + i * 64];
            const float4 bv = reinterpret_cast<const float4*>(lnb)[lane + i * 64];
            u16x4 o;
            o.x = f2bf((v[i].x - mu) * rstd * wv.x + bv.x);
            o.y = f2bf((v[i].y - mu) * rstd * wv.y + bv.y);
            o.z = f2bf((v[i].z - mu) * rstd * wv.z + bv.z);
            o.w = f2bf((v[i].w - mu) * rstd * wv.w + bv.w);
            xo[lane + i * 64] = o;
        }
    } else {
        // weight cvt: w1 = 2097152 float4s, w2 = 1048576 -> 3145728 total.
        // 2048 blocks x 256 thr = 524288 threads, 6 float4 each.
        const int idx = (bid - 2048) * 256 + t;
#pragma unroll
        for (int i = 0; i < 6; ++i) {
            const int j = idx + i * 524288;
            if (j < 2097152) {
                const float4 v = reinterpret_cast<const float4*>(w1)[j];
                u16x4 o = { f2bf(v.x), f2bf(v.y), f2bf(v.z), f2bf(v.w) };
                reinterpret_cast<u16x4*>(w1b)[j] = o;
            } else {
                const int k = j - 2097152;
                const float4 v = reinterpret_cast<const float4*>(w2)[k];
                u16x4 o = { f2bf(v.x), f2bf(v.y), f2bf(v.z), f2bf(v.w) };
                reinterpret_cast<u16x4*>(w2b)[k] = o;
            }
        }
    }
}

// =====================================================================
// ln_post2: wave-per-row post-LN + residual (2048 blocks, 4 rows each,
// shfl-only reduction).
// =====================================================================
__global__ __launch_bounds__(256) void ln_post2(
    const u16* __restrict__ op, const float* __restrict__ w,
    const float* __restrict__ b, const float* __restrict__ x,
    float* __restrict__ out)
{
    const int t = threadIdx.x;
    const int lane = t & 63, wv_ = t >> 6;
    const int row = blockIdx.x * 4 + wv_;
    const u16x4* orow = reinterpret_cast<const u16x4*>(op + (size_t)row * H_DIM);
    float4 v[4];
    float s = 0.f, s2 = 0.f;
#pragma unroll
    for (int i = 0; i < 4; ++i) {
        const u16x4 hv = orow[lane + i * 64];
        v[i].x = bf2f(hv.x); v[i].y = bf2f(hv.y);
        v[i].z = bf2f(hv.z); v[i].w = bf2f(hv.w);
        s  += v[i].x + v[i].y + v[i].z + v[i].w;
        s2 += v[i].x * v[i].x + v[i].y * v[i].y + v[i].z * v[i].z + v[i].w * v[i].w;
    }
#pragma unroll
    for (int off = 32; off > 0; off >>= 1) {
        s  += __shfl_xor(s, off);
        s2 += __shfl_xor(s2, off);
    }
    const float mu = s * (1.f / H_DIM);
    const float var = s2 * (1.f / H_DIM) - mu * mu;
    const float rstd = rsqrtf(var + 1e-5f);
    const float4* xr = reinterpret_cast<const float4*>(x + (size_t)row * H_DIM);
    float4* orow_f = reinterpret_cast<float4*>(out + (size_t)row * H_DIM);
#pragma unroll
    for (int i = 0; i < 4; ++i) {
        const float4 wv = reinterpret_cast<const float4*>(w)[lane + i * 64];
        const float4 bv = reinterpret_cast<const float4*>(b)[lane + i * 64];
        const float4 xv = xr[lane + i * 64];
        float4 o;
        o.x = (v[i].x - mu) * rstd * wv.x + bv.x + xv.x;
        o.y = (v[i].y - mu) * rstd * wv.y + bv.y + xv.y;
        o.z = (v[i].z - mu) * rstd * wv.z + bv.z + xv.z;
        o.w = (v[i].w - mu) * rstd * wv.w + bv.w + xv.w;
        orow_f[lane + i * 64] = o;
    }
}

extern "C" void kernel_launch(void* const* d_in, const int* in_sizes, int n_in,
                              void* d_out, int out_size, void* d_ws, size_t ws_size,
                              hipStream_t stream)
{
    const float* x   = (const float*)d_in[0];
    const float* lnw = (const float*)d_in[1];
    const float* lnb = (const float*)d_in[2];
    const float* w1  = (const float*)d_in[3];
    const float* b1  = (const float*)d_in[4];
    const float* w2  = (const float*)d_in[5];
    const float* b2  = (const float*)d_in[6];
    const float* pw  = (const float*)d_in[7];
    const float* pb  = (const float*)d_in[8];
    float* out = (float*)d_out;

    // Workspace layout (104 MiB peak; proven r7-r11):
    //   xln [0,16M) | w1b [16,32M) | hid [32,96M) | w2b [96,104M)
    //   opb over dead xln [0,16M) after gemm1.
    char* ws = (char*)d_ws;
    u16* xln = (u16*)(ws);
    u16* w1b = (u16*)(ws + (16u << 20));
    u16* hid = (u16*)(ws + (32u << 20));
    u16* w2b = (u16*)(ws + (96u << 20));
    u16* opb = (u16*)(ws);

    prep2<<<4096, 256, 0, stream>>>(x, lnw, lnb, xln, w1, w1b, w2, w2b);
    gemm1_gated<<<dim3(I_DIM / 128, N_ROWS / 128), 512, 0, stream>>>(xln, w1b, b1, hid);
    gemm2_k<<<dim3(H_DIM / 128, N_ROWS / 256), 512, 0, stream>>>(hid, w2b, b2, opb);
    ln_post2<<<2048, 256, 0, stream>>>(opb, pw, pb, x, out);
}